// Round 1
// baseline (245.776 us; speedup 1.0000x reference)
//
#include <hip/hip_runtime.h>
#include <math.h>

#define L_SEQ   4096
#define D_INNER 512
#define D_STATE 16
#define DT_RANK 32
#define CHUNK   32
#define NCHUNK  128          // L_SEQ / CHUNK
#define NCH     8192         // D_INNER * D_STATE

// ---------------------------------------------------------------------------
// K1: proj = x @ W_xp^T  -> dt_in (LDS), Bp, Cp (ws);  dt = softplus(dt_in@W_dt^T + b_dt)
// block = 256 threads handles 4 consecutive t-rows.
// ---------------------------------------------------------------------------
__global__ __launch_bounds__(256) void k1_proj(
    const float* __restrict__ x, const float* __restrict__ W_xp,
    const float* __restrict__ W_dt, const float* __restrict__ b_dt,
    float* __restrict__ dt, float* __restrict__ Bp, float* __restrict__ Cp)
{
    __shared__ __align__(16) float xs[4][D_INNER];
    __shared__ __align__(16) float dtin[4][DT_RANK];
    const int tid = threadIdx.x;
    const int t0 = blockIdx.x * 4;

    // stage 4 rows of x (coalesced)
    #pragma unroll
    for (int i = 0; i < 8; ++i) {
        int e = tid + i * 256;
        int r = e >> 9, k = e & 511;
        xs[r][k] = x[(t0 + r) * D_INNER + k];
    }
    __syncthreads();

    // proj: thread -> (row r, out-channel cc)
    {
        const int r  = tid >> 6;   // 0..3
        const int cc = tid & 63;   // 0..63
        const float4* wrow = (const float4*)(W_xp + cc * D_INNER);
        const float4* xr   = (const float4*)(xs[r]);
        float acc = 0.f;
        #pragma unroll 4
        for (int k4 = 0; k4 < D_INNER / 4; ++k4) {
            float4 w = wrow[k4];
            float4 v = xr[k4];
            acc += v.x * w.x + v.y * w.y + v.z * w.z + v.w * w.w;
        }
        if (cc < DT_RANK) {
            dtin[r][cc] = acc;
        } else if (cc < DT_RANK + D_STATE) {
            Bp[(t0 + r) * D_STATE + (cc - DT_RANK)] = acc;
        } else {
            Cp[(t0 + r) * D_STATE + (cc - DT_RANK - D_STATE)] = acc;
        }
    }
    __syncthreads();

    // dt = softplus(dt_in @ W_dt^T + b_dt): 4 rows x 512 cols, 2 cols/thread/row
    for (int rr = 0; rr < 4; ++rr) {
        const int d = tid * 2;
        float2 o;
        #pragma unroll
        for (int h = 0; h < 2; ++h) {
            const int dd = d + h;
            const float4* wdt = (const float4*)(W_dt + dd * DT_RANK);
            const float4* din = (const float4*)(dtin[rr]);
            float z = b_dt[dd];
            #pragma unroll
            for (int k4 = 0; k4 < DT_RANK / 4; ++k4) {
                float4 w = wdt[k4];
                float4 v = din[k4];
                z += v.x * w.x + v.y * w.y + v.z * w.z + v.w * w.w;
            }
            // stable softplus, matches log1p(exp(z))
            float sp = fmaxf(z, 0.f) + log1pf(expf(-fabsf(z)));
            ((float*)&o)[h] = sp;
        }
        *(float2*)(dt + (t0 + rr) * D_INNER + d) = o;
    }
}

// ---------------------------------------------------------------------------
// K2a: per (chunk c, 16-d block): chunk-local quantities.
//   G  = sum_j g[j],  g = alpha*Bu / max(beta^t, 1e-12)        (momentum total)
//   TA = A_cum at end of chunk
//   h_last = TA*(P1 + S_off*P2)  -> store U = TA*P1, W = TA*P2
// thread = (dl = tid>>4, n = tid&15)
// ---------------------------------------------------------------------------
__global__ __launch_bounds__(256) void k2a(
    const float* __restrict__ x, const float* __restrict__ dt,
    const float* __restrict__ Bp, const float* __restrict__ A_log,
    const float* __restrict__ alpha_p, const float* __restrict__ beta_logit_p,
    float* __restrict__ G, float* __restrict__ TA,
    float* __restrict__ U, float* __restrict__ W)
{
    __shared__ float xs[CHUNK][16], dts[CHUNK][16], Bs[CHUNK][D_STATE];
    __shared__ float bpw[CHUNK];
    const int tid = threadIdx.x;
    const int c  = blockIdx.x;
    const int d0 = blockIdx.y * 16;

    #pragma unroll
    for (int i = 0; i < 2; ++i) {
        int e = tid + i * 256;
        int t = e >> 4, dl = e & 15;
        xs[t][dl]  = x [(c * CHUNK + t) * D_INNER + d0 + dl];
        dts[t][dl] = dt[(c * CHUNK + t) * D_INNER + d0 + dl];
        Bs[t][dl]  = Bp[(c * CHUNK + t) * D_STATE + dl];
    }
    if (tid < CHUNK) {
        float betaf = 1.f / (1.f + expf(-beta_logit_p[0]));   // fp32 like ref
        double lb = log((double)betaf);
        bpw[tid] = (float)exp((double)(c * CHUNK + tid) * lb); // beta^t
    }
    __syncthreads();

    const float alpha = alpha_p[0];
    const int dl = tid >> 4, n = tid & 15;
    const float A = -expf(A_log[(d0 + dl) * D_STATE + n]);

    float LS = 0.f, csum = 0.f, P1 = 0.f, P2 = 0.f, Acum = 1.f;
    #pragma unroll
    for (int j = 0; j < CHUNK; ++j) {
        float bp  = bpw[j];
        float bpc = fmaxf(bp, 1e-12f);
        float dtv = dts[j][dl];
        float Bu  = dtv * Bs[j][n] * xs[j][dl];
        LS += alpha * Bu / bpc;
        csum += dtv * A;
        Acum = expf(csum);
        float rA = 1.f / fmaxf(Acum, 1e-8f);
        P1 += bp * LS * rA;
        P2 += bp * rA;
    }
    const int idx = c * NCH + d0 * D_STATE + tid;   // coalesced
    G[idx]  = LS;
    TA[idx] = Acum;
    U[idx]  = Acum * P1;
    W[idx]  = Acum * P2;
}

// ---------------------------------------------------------------------------
// K2b: sequential over 128 chunks, 8192 parallel channels (double precision).
//   S_off[c]      = sum of G over chunks < c
//   carry_prev[c] = carry entering chunk c;  carry' = TA*carry + U + S_off*W
// ---------------------------------------------------------------------------
__global__ __launch_bounds__(256) void k2b(
    const float* __restrict__ G, const float* __restrict__ TA,
    const float* __restrict__ U, const float* __restrict__ W,
    float* __restrict__ SoffA, float* __restrict__ CarryA)
{
    const int ch = blockIdx.x * 256 + threadIdx.x;
    double Soff = 0.0, carry = 0.0;
    for (int c = 0; c < NCHUNK; ++c) {
        const int idx = c * NCH + ch;
        SoffA[idx]  = (float)Soff;
        CarryA[idx] = (float)carry;
        carry = (double)TA[idx] * carry + (double)U[idx] + Soff * (double)W[idx];
        Soff += (double)G[idx];
    }
}

// ---------------------------------------------------------------------------
// K2c: recompute within-chunk state with offsets known, emit output.
//   v[j]     = beta^t * (S_off + LS[j])
//   h_full   = A_cum*P + A_cum*carry_prev,  P = cumsum(v / max(A_cum,1e-8))
//   y[t,d]   = sum_n h_full * Cp[t,n];   out = y + D_param*x
// ---------------------------------------------------------------------------
__global__ __launch_bounds__(256) void k2c(
    const float* __restrict__ x, const float* __restrict__ dt,
    const float* __restrict__ Bp, const float* __restrict__ Cp,
    const float* __restrict__ A_log, const float* __restrict__ D_param,
    const float* __restrict__ alpha_p, const float* __restrict__ beta_logit_p,
    const float* __restrict__ SoffA, const float* __restrict__ CarryA,
    float* __restrict__ out)
{
    __shared__ float xs[CHUNK][16], dts[CHUNK][16], Bs[CHUNK][16], Cs[CHUNK][16];
    __shared__ float bpw[CHUNK];
    __shared__ float ys[CHUNK][16];
    const int tid = threadIdx.x;
    const int c  = blockIdx.x;
    const int d0 = blockIdx.y * 16;

    #pragma unroll
    for (int i = 0; i < 2; ++i) {
        int e = tid + i * 256;
        int t = e >> 4, dl = e & 15;
        xs[t][dl]  = x [(c * CHUNK + t) * D_INNER + d0 + dl];
        dts[t][dl] = dt[(c * CHUNK + t) * D_INNER + d0 + dl];
        Bs[t][dl]  = Bp[(c * CHUNK + t) * D_STATE + dl];
        Cs[t][dl]  = Cp[(c * CHUNK + t) * D_STATE + dl];
    }
    if (tid < CHUNK) {
        float betaf = 1.f / (1.f + expf(-beta_logit_p[0]));
        double lb = log((double)betaf);
        bpw[tid] = (float)exp((double)(c * CHUNK + tid) * lb);
    }
    __syncthreads();

    const float alpha = alpha_p[0];
    const int dl = tid >> 4, n = tid & 15;
    const float A = -expf(A_log[(d0 + dl) * D_STATE + n]);

    const int idx = c * NCH + d0 * D_STATE + tid;
    const float Soff  = SoffA[idx];
    const float cprev = CarryA[idx];

    float LS = 0.f, csum = 0.f, P = 0.f;
    #pragma unroll
    for (int j = 0; j < CHUNK; ++j) {
        float bp  = bpw[j];
        float bpc = fmaxf(bp, 1e-12f);
        float dtv = dts[j][dl];
        float Bu  = dtv * Bs[j][n] * xs[j][dl];
        LS += alpha * Bu / bpc;
        float v = bp * (Soff + LS);          // matches ref association
        csum += dtv * A;
        float Acum = expf(csum);
        P += v / fmaxf(Acum, 1e-8f);
        float hf = Acum * P + Acum * cprev;  // h_intra + A_cum*carry_prev
        float contrib = hf * Cs[j][n];
        // reduce over n within each 16-lane group
        contrib += __shfl_xor(contrib, 1);
        contrib += __shfl_xor(contrib, 2);
        contrib += __shfl_xor(contrib, 4);
        contrib += __shfl_xor(contrib, 8);
        if (n == 0) ys[j][dl] = contrib;
    }
    __syncthreads();

    #pragma unroll
    for (int i = 0; i < 2; ++i) {
        int e = tid + i * 256;
        int t = e >> 4, dl2 = e & 15;
        int gd = d0 + dl2;
        out[(c * CHUNK + t) * D_INNER + gd] = ys[t][dl2] + D_param[gd] * xs[t][dl2];
    }
}

// ---------------------------------------------------------------------------
extern "C" void kernel_launch(void* const* d_in, const int* in_sizes, int n_in,
                              void* d_out, int out_size, void* d_ws, size_t ws_size,
                              hipStream_t stream)
{
    const float* x          = (const float*)d_in[0];
    const float* W_xp       = (const float*)d_in[1];
    const float* W_dt       = (const float*)d_in[2];
    const float* b_dt       = (const float*)d_in[3];
    const float* A_log      = (const float*)d_in[4];
    const float* D_param    = (const float*)d_in[5];
    const float* alpha      = (const float*)d_in[6];
    const float* beta_logit = (const float*)d_in[7];
    float* out = (float*)d_out;

    float* ws = (float*)d_ws;
    float* dt = ws;                         // 4096*512   = 2,097,152
    float* Bp = dt + (size_t)L_SEQ * D_INNER;      // 4096*16
    float* Cp = Bp + (size_t)L_SEQ * D_STATE;      // 4096*16
    float* G  = Cp + (size_t)L_SEQ * D_STATE;      // 128*8192
    float* TA = G  + (size_t)NCHUNK * NCH;
    float* U  = TA + (size_t)NCHUNK * NCH;
    float* W  = U  + (size_t)NCHUNK * NCH;
    float* So = W  + (size_t)NCHUNK * NCH;
    float* Ca = So + (size_t)NCHUNK * NCH;
    // total = 8,519,680 floats ≈ 34.1 MB

    k1_proj<<<L_SEQ / 4, 256, 0, stream>>>(x, W_xp, W_dt, b_dt, dt, Bp, Cp);
    k2a<<<dim3(NCHUNK, D_INNER / 16), 256, 0, stream>>>(
        x, dt, Bp, A_log, alpha, beta_logit, G, TA, U, W);
    k2b<<<NCH / 256, 256, 0, stream>>>(G, TA, U, W, So, Ca);
    k2c<<<dim3(NCHUNK, D_INNER / 16), 256, 0, stream>>>(
        x, dt, Bp, Cp, A_log, D_param, alpha, beta_logit, So, Ca, out);
}

// Round 2
// 169.194 us; speedup vs baseline: 1.4526x; 1.4526x over previous
//
#include <hip/hip_runtime.h>
#include <math.h>

#define L_SEQ   4096
#define D_INNER 512
#define D_STATE 16
#define DT_RANK 32
#define CHUNK   32
#define NCHUNK  128          // L_SEQ / CHUNK
#define NCH     8192         // D_INNER * D_STATE
#define LN_1EM8 -18.420681f  // ln(1e-8)

// ---------------------------------------------------------------------------
// K1: tiled fp32 GEMM. Phase 1: proj = x @ W_xp^T (64 out-ch) for 32 rows/block.
// Phase 2: dt = softplus(dt_in @ W_dt^T + b_dt) for the same 32 rows.
// Grid: 128 blocks x 256 threads.
// ---------------------------------------------------------------------------
__global__ __launch_bounds__(256) void k1_proj(
    const float* __restrict__ x, const float* __restrict__ W_xp,
    const float* __restrict__ W_dt, const float* __restrict__ b_dt,
    float* __restrict__ dt_out, float* __restrict__ Bp, float* __restrict__ Cp)
{
    __shared__ __align__(16) float xs[32][36];    // rows x k-chunk (pad 36)
    __shared__ __align__(16) float wsd[64][36];   // cc   x k-chunk
    __shared__ __align__(16) float dtin[32][36];  // rows x rank

    const int tid = threadIdx.x;
    const int t0  = blockIdx.x * 32;

    float acc[2][4] = {{0.f,0.f,0.f,0.f},{0.f,0.f,0.f,0.f}};
    const int rt = (tid & 15) * 2;   // rows rt, rt+1
    const int ct = (tid >> 4) * 4;   // cc ct..ct+3

    for (int kc = 0; kc < D_INNER; kc += 32) {
        // stage x chunk: 32 rows x 32 k
        {
            int r  = tid >> 3;
            int k4 = (tid & 7) << 2;
            *(float4*)&xs[r][k4] =
                *(const float4*)&x[(size_t)(t0 + r) * D_INNER + kc + k4];
        }
        // stage W chunk: 64 cc x 32 k
        #pragma unroll
        for (int i = 0; i < 2; ++i) {
            int e   = tid + i * 256;
            int ccw = e >> 3;
            int kw  = (e & 7) << 2;
            *(float4*)&wsd[ccw][kw] =
                *(const float4*)&W_xp[(size_t)ccw * D_INNER + kc + kw];
        }
        __syncthreads();

        #pragma unroll
        for (int k = 0; k < 32; k += 4) {
            float4 x0 = *(const float4*)&xs[rt][k];
            float4 x1 = *(const float4*)&xs[rt + 1][k];
            float4 w0 = *(const float4*)&wsd[ct][k];
            float4 w1 = *(const float4*)&wsd[ct + 1][k];
            float4 w2 = *(const float4*)&wsd[ct + 2][k];
            float4 w3 = *(const float4*)&wsd[ct + 3][k];
            acc[0][0] += x0.x*w0.x + x0.y*w0.y + x0.z*w0.z + x0.w*w0.w;
            acc[0][1] += x0.x*w1.x + x0.y*w1.y + x0.z*w1.z + x0.w*w1.w;
            acc[0][2] += x0.x*w2.x + x0.y*w2.y + x0.z*w2.z + x0.w*w2.w;
            acc[0][3] += x0.x*w3.x + x0.y*w3.y + x0.z*w3.z + x0.w*w3.w;
            acc[1][0] += x1.x*w0.x + x1.y*w0.y + x1.z*w0.z + x1.w*w0.w;
            acc[1][1] += x1.x*w1.x + x1.y*w1.y + x1.z*w1.z + x1.w*w1.w;
            acc[1][2] += x1.x*w2.x + x1.y*w2.y + x1.z*w2.z + x1.w*w2.w;
            acc[1][3] += x1.x*w3.x + x1.y*w3.y + x1.z*w3.z + x1.w*w3.w;
        }
        __syncthreads();
    }

    // scatter proj outputs
    #pragma unroll
    for (int rr = 0; rr < 2; ++rr) {
        #pragma unroll
        for (int cj = 0; cj < 4; ++cj) {
            int cc = ct + cj, r = rt + rr;
            float a = acc[rr][cj];
            if (cc < DT_RANK)               dtin[r][cc] = a;
            else if (cc < DT_RANK + D_STATE) Bp[(size_t)(t0 + r) * D_STATE + (cc - DT_RANK)] = a;
            else                             Cp[(size_t)(t0 + r) * D_STATE + (cc - DT_RANK - D_STATE)] = a;
        }
    }
    __syncthreads();

    // phase 2: dt = softplus(dtin @ W_dt^T + b_dt). thread -> d-cols {2*tid, 2*tid+1}
    const int dA = tid * 2, dB = tid * 2 + 1;
    float4 wa[8], wb[8];
    #pragma unroll
    for (int q = 0; q < 8; ++q) {
        wa[q] = *(const float4*)&W_dt[(size_t)dA * DT_RANK + q * 4];
        wb[q] = *(const float4*)&W_dt[(size_t)dB * DT_RANK + q * 4];
    }
    const float bA = b_dt[dA], bB = b_dt[dB];
    for (int r = 0; r < 32; ++r) {
        float zA = bA, zB = bB;
        #pragma unroll
        for (int q = 0; q < 8; ++q) {
            float4 dn = *(const float4*)&dtin[r][q * 4];   // wave-uniform broadcast
            zA += dn.x*wa[q].x + dn.y*wa[q].y + dn.z*wa[q].z + dn.w*wa[q].w;
            zB += dn.x*wb[q].x + dn.y*wb[q].y + dn.z*wb[q].z + dn.w*wb[q].w;
        }
        float2 o;
        o.x = fmaxf(zA, 0.f) + log1pf(expf(-fabsf(zA)));
        o.y = fmaxf(zB, 0.f) + log1pf(expf(-fabsf(zB)));
        *(float2*)&dt_out[(size_t)(t0 + r) * D_INNER + dA] = o;
    }
}

// ---------------------------------------------------------------------------
// K2a: per (chunk c, 16-d block): chunk-local sums.
//   G  = sum g,  g = alpha*Bu/max(beta^t,1e-12)
//   TA = A_cum at chunk end
//   U  = TA*P1, W = TA*P2   (h_last = U + S_off*W, linear in momentum offset)
// thread = (dl = tid>>4, n = tid&15). GTUW packed float4 for k2b.
// ---------------------------------------------------------------------------
__global__ __launch_bounds__(256) void k2a(
    const float* __restrict__ x, const float* __restrict__ dt,
    const float* __restrict__ Bp, const float* __restrict__ A_log,
    const float* __restrict__ alpha_p, const float* __restrict__ beta_logit_p,
    float4* __restrict__ GTUW)
{
    __shared__ __align__(16) float xs_t[16][36], dts_t[16][36], Bs_t[16][36];
    __shared__ __align__(16) float bpw[32], aib[32];
    const int tid = threadIdx.x;
    const int c   = blockIdx.x;
    const int d0  = blockIdx.y * 16;

    #pragma unroll
    for (int i = 0; i < 2; ++i) {
        int e = tid + i * 256;
        int t = e >> 4, q = e & 15;
        xs_t [q][t] = x [(size_t)(c * CHUNK + t) * D_INNER + d0 + q];
        dts_t[q][t] = dt[(size_t)(c * CHUNK + t) * D_INNER + d0 + q];
        Bs_t [q][t] = Bp[(size_t)(c * CHUNK + t) * D_STATE + q];
    }
    if (tid < CHUNK) {
        float betaf = 1.f / (1.f + expf(-beta_logit_p[0]));
        double lb = log((double)betaf);
        float bp = (float)exp((double)(c * CHUNK + tid) * lb);
        bpw[tid] = bp;
        aib[tid] = alpha_p[0] / fmaxf(bp, 1e-12f);
    }
    __syncthreads();

    const int dl = tid >> 4, n = tid & 15;
    const float A = -expf(A_log[(d0 + dl) * D_STATE + n]);

    float LS = 0.f, csum = 0.f, P1 = 0.f, P2 = 0.f;
    #pragma unroll
    for (int j = 0; j < CHUNK; j += 4) {
        float4 dt4 = *(const float4*)&dts_t[dl][j];
        float4 xx4 = *(const float4*)&xs_t [dl][j];
        float4 BB4 = *(const float4*)&Bs_t [n][j];
        float4 bp4 = *(const float4*)&bpw[j];
        float4 ai4 = *(const float4*)&aib[j];
        #pragma unroll
        for (int u = 0; u < 4; ++u) {
            float dtv = ((const float*)&dt4)[u];
            float xv  = ((const float*)&xx4)[u];
            float Bv  = ((const float*)&BB4)[u];
            float bp  = ((const float*)&bp4)[u];
            float ai  = ((const float*)&ai4)[u];
            float Bu  = dtv * Bv * xv;
            LS   = fmaf(ai, Bu, LS);
            csum = fmaf(dtv, A, csum);
            float rA = (csum < LN_1EM8) ? 1e8f : __expf(-csum);
            float t1 = bp * rA;
            P1 = fmaf(t1, LS, P1);
            P2 += t1;
        }
    }
    float TA = __expf(csum);
    float4 o; o.x = LS; o.y = TA; o.z = TA * P1; o.w = TA * P2;
    GTUW[(size_t)c * NCH + d0 * D_STATE + tid] = o;
}

// ---------------------------------------------------------------------------
// K2b: sequential over 128 chunks, 8192 parallel channels (fp64 accum).
// ---------------------------------------------------------------------------
__global__ __launch_bounds__(64) void k2b(
    const float4* __restrict__ GTUW, float2* __restrict__ SC)
{
    const int ch = blockIdx.x * 64 + threadIdx.x;
    double Soff = 0.0, carry = 0.0;
    for (int c = 0; c < NCHUNK; ++c) {
        const size_t idx = (size_t)c * NCH + ch;
        float2 sc; sc.x = (float)Soff; sc.y = (float)carry;
        SC[idx] = sc;
        float4 g = GTUW[idx];
        carry = (double)g.y * carry + (double)g.z + Soff * (double)g.w;
        Soff += (double)g.x;
    }
}

// ---------------------------------------------------------------------------
// K2c: recompute within-chunk state with offsets known, emit y + D*x.
// Per-j contributions scattered to LDS (pad 20), reduced over n afterwards.
// ---------------------------------------------------------------------------
__global__ __launch_bounds__(256) void k2c(
    const float* __restrict__ x, const float* __restrict__ dt,
    const float* __restrict__ Bp, const float* __restrict__ Cp,
    const float* __restrict__ A_log, const float* __restrict__ D_param,
    const float* __restrict__ alpha_p, const float* __restrict__ beta_logit_p,
    const float2* __restrict__ SC, float* __restrict__ out)
{
    __shared__ __align__(16) float xs_t[16][36], dts_t[16][36];
    __shared__ __align__(16) float Bs_t[16][36], Cs_t[16][36];
    __shared__ __align__(16) float bpw[32], aib[32];
    __shared__ __align__(16) float ys2[CHUNK * 16][20];   // (j,dl) x n, pad 20
    const int tid = threadIdx.x;
    const int c   = blockIdx.x;
    const int d0  = blockIdx.y * 16;

    #pragma unroll
    for (int i = 0; i < 2; ++i) {
        int e = tid + i * 256;
        int t = e >> 4, q = e & 15;
        xs_t [q][t] = x [(size_t)(c * CHUNK + t) * D_INNER + d0 + q];
        dts_t[q][t] = dt[(size_t)(c * CHUNK + t) * D_INNER + d0 + q];
        Bs_t [q][t] = Bp[(size_t)(c * CHUNK + t) * D_STATE + q];
        Cs_t [q][t] = Cp[(size_t)(c * CHUNK + t) * D_STATE + q];
    }
    if (tid < CHUNK) {
        float betaf = 1.f / (1.f + expf(-beta_logit_p[0]));
        double lb = log((double)betaf);
        float bp = (float)exp((double)(c * CHUNK + tid) * lb);
        bpw[tid] = bp;
        aib[tid] = alpha_p[0] / fmaxf(bp, 1e-12f);
    }
    __syncthreads();

    const int dl = tid >> 4, n = tid & 15;
    const float A = -expf(A_log[(d0 + dl) * D_STATE + n]);

    float2 sc = SC[(size_t)c * NCH + d0 * D_STATE + tid];
    const float Soff = sc.x, cprev = sc.y;

    float LS = 0.f, csum = 0.f, P = 0.f;
    #pragma unroll
    for (int j = 0; j < CHUNK; j += 4) {
        float4 dt4 = *(const float4*)&dts_t[dl][j];
        float4 xx4 = *(const float4*)&xs_t [dl][j];
        float4 BB4 = *(const float4*)&Bs_t [n][j];
        float4 CC4 = *(const float4*)&Cs_t [n][j];
        float4 bp4 = *(const float4*)&bpw[j];
        float4 ai4 = *(const float4*)&aib[j];
        #pragma unroll
        for (int u = 0; u < 4; ++u) {
            float dtv = ((const float*)&dt4)[u];
            float xv  = ((const float*)&xx4)[u];
            float Bv  = ((const float*)&BB4)[u];
            float Cv  = ((const float*)&CC4)[u];
            float bp  = ((const float*)&bp4)[u];
            float ai  = ((const float*)&ai4)[u];
            float Bu  = dtv * Bv * xv;
            LS   = fmaf(ai, Bu, LS);
            float v = bp * (Soff + LS);
            csum = fmaf(dtv, A, csum);
            float Acum = __expf(csum);
            float rA = (csum < LN_1EM8) ? 1e8f : __expf(-csum);
            P = fmaf(v, rA, P);
            float hf = Acum * (P + cprev);
            ys2[(j + u) * 16 + dl][n] = hf * Cv;
        }
    }
    __syncthreads();

    #pragma unroll
    for (int i = 0; i < 2; ++i) {
        int p  = tid + i * 256;        // 0..511 = (j, dl)
        int j  = p >> 4, dl2 = p & 15;
        const float* row = ys2[p];
        float4 a0 = ((const float4*)row)[0];
        float4 a1 = ((const float4*)row)[1];
        float4 a2 = ((const float4*)row)[2];
        float4 a3 = ((const float4*)row)[3];
        float s = a0.x+a0.y+a0.z+a0.w + a1.x+a1.y+a1.z+a1.w
                + a2.x+a2.y+a2.z+a2.w + a3.x+a3.y+a3.z+a3.w;
        int gd = d0 + dl2;
        out[(size_t)(c * CHUNK + j) * D_INNER + gd] = s + D_param[gd] * xs_t[dl2][j];
    }
}

// ---------------------------------------------------------------------------
extern "C" void kernel_launch(void* const* d_in, const int* in_sizes, int n_in,
                              void* d_out, int out_size, void* d_ws, size_t ws_size,
                              hipStream_t stream)
{
    const float* x          = (const float*)d_in[0];
    const float* W_xp       = (const float*)d_in[1];
    const float* W_dt       = (const float*)d_in[2];
    const float* b_dt       = (const float*)d_in[3];
    const float* A_log      = (const float*)d_in[4];
    const float* D_param    = (const float*)d_in[5];
    const float* alpha      = (const float*)d_in[6];
    const float* beta_logit = (const float*)d_in[7];
    float* out = (float*)d_out;

    float* ws = (float*)d_ws;
    float*  dt   = ws;                                   // 4096*512 = 2,097,152 floats
    float*  Bp   = dt + (size_t)L_SEQ * D_INNER;         // 65,536
    float*  Cp   = Bp + (size_t)L_SEQ * D_STATE;         // 65,536
    float4* GTUW = (float4*)(Cp + (size_t)L_SEQ * D_STATE);        // 128*8192 float4
    float2* SC   = (float2*)((float*)GTUW + (size_t)4 * NCHUNK * NCH); // 128*8192 float2
    // total = 2,228,224 + 4,194,304 + 2,097,152 floats ≈ 34.1 MB

    k1_proj<<<L_SEQ / 32, 256, 0, stream>>>(x, W_xp, W_dt, b_dt, dt, Bp, Cp);
    k2a<<<dim3(NCHUNK, D_INNER / 16), 256, 0, stream>>>(
        x, dt, Bp, A_log, alpha, beta_logit, GTUW);
    k2b<<<NCH / 64, 64, 0, stream>>>(GTUW, SC);
    k2c<<<dim3(NCHUNK, D_INNER / 16), 256, 0, stream>>>(
        x, dt, Bp, Cp, A_log, D_param, alpha, beta_logit, SC, out);
}

// Round 3
// 157.082 us; speedup vs baseline: 1.5646x; 1.0771x over previous
//
#include <hip/hip_runtime.h>
#include <math.h>

#define L_SEQ   4096
#define D_INNER 512
#define D_STATE 16
#define DT_RANK 32
#define CHUNK   32
#define NCHUNK  128          // L_SEQ / CHUNK
#define NCH     8192         // D_INNER * D_STATE
#define LN_1EM8 -18.420681f  // ln(1e-8)

// ---------------------------------------------------------------------------
// K1a: split-K GEMM: proj_part[kb] = x[:, kb*64:+64] @ W_xp[:, kb*64:+64]^T
// grid (64 row-tiles, 8 k-splits) x 256 thr. 4x4 register tiles.
// ---------------------------------------------------------------------------
__global__ __launch_bounds__(256) void k1a(
    const float* __restrict__ x, const float* __restrict__ W_xp,
    float* __restrict__ proj_part)
{
    __shared__ __align__(16) float xs_t[64][68];   // [k][row]
    __shared__ __align__(16) float ws_t[64][68];   // [k][cc]
    const int tid = threadIdx.x;
    const int t0  = blockIdx.x * 64;
    const int k0  = blockIdx.y * 64;

    #pragma unroll
    for (int i = 0; i < 4; ++i) {
        int e = tid + i * 256;
        int r = e >> 4, k4 = (e & 15) << 2;
        float4 v = *(const float4*)&x[(size_t)(t0 + r) * D_INNER + k0 + k4];
        xs_t[k4 + 0][r] = v.x; xs_t[k4 + 1][r] = v.y;
        xs_t[k4 + 2][r] = v.z; xs_t[k4 + 3][r] = v.w;
        float4 w = *(const float4*)&W_xp[(size_t)r * D_INNER + k0 + k4];
        ws_t[k4 + 0][r] = w.x; ws_t[k4 + 1][r] = w.y;
        ws_t[k4 + 2][r] = w.z; ws_t[k4 + 3][r] = w.w;
    }
    __syncthreads();

    const int tr = (tid & 15) << 2;   // 4 rows
    const int tc = (tid >> 4) << 2;   // 4 cc
    float a00=0,a01=0,a02=0,a03=0, a10=0,a11=0,a12=0,a13=0;
    float a20=0,a21=0,a22=0,a23=0, a30=0,a31=0,a32=0,a33=0;

    #pragma unroll 4
    for (int k = 0; k < 64; ++k) {
        float4 xv = *(const float4*)&xs_t[k][tr];
        float4 wv = *(const float4*)&ws_t[k][tc];
        a00 = fmaf(xv.x, wv.x, a00); a01 = fmaf(xv.x, wv.y, a01);
        a02 = fmaf(xv.x, wv.z, a02); a03 = fmaf(xv.x, wv.w, a03);
        a10 = fmaf(xv.y, wv.x, a10); a11 = fmaf(xv.y, wv.y, a11);
        a12 = fmaf(xv.y, wv.z, a12); a13 = fmaf(xv.y, wv.w, a13);
        a20 = fmaf(xv.z, wv.x, a20); a21 = fmaf(xv.z, wv.y, a21);
        a22 = fmaf(xv.z, wv.z, a22); a23 = fmaf(xv.z, wv.w, a23);
        a30 = fmaf(xv.w, wv.x, a30); a31 = fmaf(xv.w, wv.y, a31);
        a32 = fmaf(xv.w, wv.z, a32); a33 = fmaf(xv.w, wv.w, a33);
    }
    float* base = proj_part + (size_t)blockIdx.y * (L_SEQ * 64);
    float4 o;
    o.x=a00; o.y=a01; o.z=a02; o.w=a03; *(float4*)&base[(t0+tr+0)*64 + tc] = o;
    o.x=a10; o.y=a11; o.z=a12; o.w=a13; *(float4*)&base[(t0+tr+1)*64 + tc] = o;
    o.x=a20; o.y=a21; o.z=a22; o.w=a23; *(float4*)&base[(t0+tr+2)*64 + tc] = o;
    o.x=a30; o.y=a31; o.z=a32; o.w=a33; *(float4*)&base[(t0+tr+3)*64 + tc] = o;
}

// ---------------------------------------------------------------------------
// K1b: reduce the 8 K-split partials -> proj; scatter Bp/Cp; dt = softplus(
// dtin @ W_dt^T + b_dt). grid 256 x 256 thr, 16 rows/block.
// ---------------------------------------------------------------------------
__global__ __launch_bounds__(256) void k1b(
    const float* __restrict__ proj_part, const float* __restrict__ W_dt,
    const float* __restrict__ b_dt, float* __restrict__ dt_out,
    float* __restrict__ Bp, float* __restrict__ Cp)
{
    __shared__ __align__(16) float ps[16][68];
    const int tid = threadIdx.x;
    const int t0  = blockIdx.x * 16;

    {   // sum partials: one float4 per thread (16 rows x 16 f4-cols)
        const int r = tid >> 4, q = (tid & 15) << 2;
        float4 s = {0.f, 0.f, 0.f, 0.f};
        #pragma unroll
        for (int p = 0; p < 8; ++p) {
            float4 v = *(const float4*)&proj_part[(size_t)p * (L_SEQ * 64) + (t0 + r) * 64 + q];
            s.x += v.x; s.y += v.y; s.z += v.z; s.w += v.w;
        }
        *(float4*)&ps[r][q] = s;
    }
    __syncthreads();

    {   // Bp / Cp scatter
        const int r = tid >> 4, n = tid & 15;
        Bp[(size_t)(t0 + r) * D_STATE + n] = ps[r][32 + n];
        Cp[(size_t)(t0 + r) * D_STATE + n] = ps[r][48 + n];
    }

    // dt phase: thread -> cols {2*tid, 2*tid+1}
    const int dA = tid * 2, dB = tid * 2 + 1;
    float4 wa[8], wb[8];
    #pragma unroll
    for (int q = 0; q < 8; ++q) {
        wa[q] = *(const float4*)&W_dt[(size_t)dA * DT_RANK + q * 4];
        wb[q] = *(const float4*)&W_dt[(size_t)dB * DT_RANK + q * 4];
    }
    const float bA = b_dt[dA], bB = b_dt[dB];
    for (int r = 0; r < 16; ++r) {
        float zA = bA, zB = bB;
        #pragma unroll
        for (int q = 0; q < 8; ++q) {
            float4 dn = *(const float4*)&ps[r][q * 4];   // broadcast
            zA += dn.x*wa[q].x + dn.y*wa[q].y + dn.z*wa[q].z + dn.w*wa[q].w;
            zB += dn.x*wb[q].x + dn.y*wb[q].y + dn.z*wb[q].z + dn.w*wb[q].w;
        }
        float2 o;
        o.x = fmaxf(zA, 0.f) + log1pf(expf(-fabsf(zA)));
        o.y = fmaxf(zB, 0.f) + log1pf(expf(-fabsf(zB)));
        *(float2*)&dt_out[(size_t)(t0 + r) * D_INNER + dA] = o;
    }
}

// ---------------------------------------------------------------------------
// K2a: chunk-local sums. Block = (chunk c, 64-d slab). thread = (dl, 4 n's).
//   G = sum alpha*Bu/clip(beta^t); TA = A_cum end; U = TA*P1; W = TA*P2.
// ---------------------------------------------------------------------------
__global__ __launch_bounds__(256) void k2a(
    const float* __restrict__ x, const float* __restrict__ dt,
    const float* __restrict__ Bp, const float* __restrict__ A_log,
    const float* __restrict__ alpha_p, const float* __restrict__ beta_logit_p,
    float4* __restrict__ GTUW)
{
    __shared__ float xs[CHUNK][65], dts[CHUNK][65];
    __shared__ __align__(16) float Bs[CHUNK][20];
    __shared__ float bpw[CHUNK], aib[CHUNK];
    const int tid = threadIdx.x;
    const int c   = blockIdx.x;
    const int d0  = blockIdx.y * 64;

    #pragma unroll
    for (int i = 0; i < 8; ++i) {
        int e = tid + i * 256;
        int t = e >> 6, dl = e & 63;
        xs [t][dl] = x [(size_t)(c * CHUNK + t) * D_INNER + d0 + dl];
        dts[t][dl] = dt[(size_t)(c * CHUNK + t) * D_INNER + d0 + dl];
    }
    #pragma unroll
    for (int i = 0; i < 2; ++i) {
        int e = tid + i * 256;
        int t = e >> 4, n = e & 15;
        Bs[t][n] = Bp[(size_t)(c * CHUNK + t) * D_STATE + n];
    }
    if (tid < CHUNK) {
        float betaf = 1.f / (1.f + expf(-beta_logit_p[0]));
        double lb = log((double)betaf);
        float bp = (float)exp((double)(c * CHUNK + tid) * lb);
        bpw[tid] = bp;
        aib[tid] = alpha_p[0] / fmaxf(bp, 1e-12f);
    }
    __syncthreads();

    const int dl = tid >> 2, n0 = (tid & 3) << 2;
    float A[4], LS[4] = {0,0,0,0}, cs[4] = {0,0,0,0};
    float P1[4] = {0,0,0,0}, P2[4] = {0,0,0,0};
    #pragma unroll
    for (int i = 0; i < 4; ++i)
        A[i] = -expf(A_log[(size_t)(d0 + dl) * D_STATE + n0 + i]);

    #pragma unroll 4
    for (int j = 0; j < CHUNK; ++j) {
        float dtv = dts[j][dl];
        float xv  = xs[j][dl];
        float bp  = bpw[j];
        float ai  = aib[j];
        float4 Bv = *(const float4*)&Bs[j][n0];
        #pragma unroll
        for (int i = 0; i < 4; ++i) {
            float Bu = dtv * ((const float*)&Bv)[i] * xv;
            LS[i] = fmaf(ai, Bu, LS[i]);
            cs[i] = fmaf(dtv, A[i], cs[i]);
            float rA = (cs[i] < LN_1EM8) ? 1e8f : __expf(-cs[i]);
            float t1 = bp * rA;
            P1[i] = fmaf(t1, LS[i], P1[i]);
            P2[i] += t1;
        }
    }
    #pragma unroll
    for (int i = 0; i < 4; ++i) {
        float TA = __expf(cs[i]);
        float4 o; o.x = LS[i]; o.y = TA; o.z = TA * P1[i]; o.w = TA * P2[i];
        GTUW[(size_t)c * NCH + (d0 + dl) * D_STATE + n0 + i] = o;
    }
}

// ---------------------------------------------------------------------------
// K2b: 128-step serial scan, 8192 channels, depth-4 prefetch (fp64 accum).
// ---------------------------------------------------------------------------
__global__ __launch_bounds__(64) void k2b(
    const float4* __restrict__ GTUW, float2* __restrict__ SC)
{
    const int ch = blockIdx.x * 64 + threadIdx.x;
    double Soff = 0.0, carry = 0.0;
    float4 buf[4];
    #pragma unroll
    for (int p = 0; p < 4; ++p) buf[p] = GTUW[(size_t)p * NCH + ch];
    #pragma unroll 4
    for (int c = 0; c < NCHUNK; ++c) {
        float4 g = buf[c & 3];
        if (c + 4 < NCHUNK) buf[c & 3] = GTUW[(size_t)(c + 4) * NCH + ch];
        float2 sc; sc.x = (float)Soff; sc.y = (float)carry;
        SC[(size_t)c * NCH + ch] = sc;
        carry = (double)g.y * carry + (double)g.z + Soff * (double)g.w;
        Soff += (double)g.x;
    }
}

// ---------------------------------------------------------------------------
// K2c: recompute within-chunk state with offsets known, emit y + D*x.
// Block = (chunk c, 64-d slab). thread = (dl, 4 n's); n-reduce: in-register
// over the thread's 4 n + 2 shuffles across the lane-group of 4.
// ---------------------------------------------------------------------------
__global__ __launch_bounds__(256) void k2c(
    const float* __restrict__ x, const float* __restrict__ dt,
    const float* __restrict__ Bp, const float* __restrict__ Cp,
    const float* __restrict__ A_log, const float* __restrict__ D_param,
    const float* __restrict__ alpha_p, const float* __restrict__ beta_logit_p,
    const float2* __restrict__ SC, float* __restrict__ out)
{
    __shared__ float xs[CHUNK][65], dts[CHUNK][65];
    __shared__ __align__(16) float Bs[CHUNK][20], Cs[CHUNK][20];
    __shared__ float bpw[CHUNK], aib[CHUNK];
    __shared__ float ys[CHUNK][65];
    const int tid = threadIdx.x;
    const int c   = blockIdx.x;
    const int d0  = blockIdx.y * 64;

    #pragma unroll
    for (int i = 0; i < 8; ++i) {
        int e = tid + i * 256;
        int t = e >> 6, dl = e & 63;
        xs [t][dl] = x [(size_t)(c * CHUNK + t) * D_INNER + d0 + dl];
        dts[t][dl] = dt[(size_t)(c * CHUNK + t) * D_INNER + d0 + dl];
    }
    #pragma unroll
    for (int i = 0; i < 2; ++i) {
        int e = tid + i * 256;
        int t = e >> 4, n = e & 15;
        Bs[t][n] = Bp[(size_t)(c * CHUNK + t) * D_STATE + n];
        Cs[t][n] = Cp[(size_t)(c * CHUNK + t) * D_STATE + n];
    }
    if (tid < CHUNK) {
        float betaf = 1.f / (1.f + expf(-beta_logit_p[0]));
        double lb = log((double)betaf);
        float bp = (float)exp((double)(c * CHUNK + tid) * lb);
        bpw[tid] = bp;
        aib[tid] = alpha_p[0] / fmaxf(bp, 1e-12f);
    }
    __syncthreads();

    const int dl = tid >> 2, n0 = (tid & 3) << 2;
    float A[4], LS[4] = {0,0,0,0}, cs[4] = {0,0,0,0}, P[4] = {0,0,0,0};
    float So[4], Cv0[4];
    #pragma unroll
    for (int i = 0; i < 4; ++i)
        A[i] = -expf(A_log[(size_t)(d0 + dl) * D_STATE + n0 + i]);
    #pragma unroll
    for (int i = 0; i < 4; ++i) {
        float2 sc = SC[(size_t)c * NCH + (d0 + dl) * D_STATE + n0 + i];
        So[i] = sc.x; Cv0[i] = sc.y;   // Soff, carry_prev
    }

    #pragma unroll 4
    for (int j = 0; j < CHUNK; ++j) {
        float dtv = dts[j][dl];
        float xv  = xs[j][dl];
        float bp  = bpw[j];
        float ai  = aib[j];
        float4 Bv = *(const float4*)&Bs[j][n0];
        float4 Cv = *(const float4*)&Cs[j][n0];
        float contrib = 0.f;
        #pragma unroll
        for (int i = 0; i < 4; ++i) {
            float Bu = dtv * ((const float*)&Bv)[i] * xv;
            LS[i] = fmaf(ai, Bu, LS[i]);
            float v = bp * (So[i] + LS[i]);
            cs[i] = fmaf(dtv, A[i], cs[i]);
            float Acum = __expf(cs[i]);
            float rA = (cs[i] < LN_1EM8) ? 1e8f : __expf(-cs[i]);
            P[i] = fmaf(v, rA, P[i]);
            float hf = Acum * (P[i] + Cv0[i]);
            contrib = fmaf(hf, ((const float*)&Cv)[i], contrib);
        }
        contrib += __shfl_xor(contrib, 1);
        contrib += __shfl_xor(contrib, 2);
        if ((tid & 3) == 0) ys[j][dl] = contrib;
    }
    __syncthreads();

    #pragma unroll
    for (int i = 0; i < 8; ++i) {
        int e = tid + i * 256;
        int t = e >> 6, d2 = e & 63;
        int gd = d0 + d2;
        out[(size_t)(c * CHUNK + t) * D_INNER + gd] = ys[t][d2] + D_param[gd] * xs[t][d2];
    }
}

// ---------------------------------------------------------------------------
extern "C" void kernel_launch(void* const* d_in, const int* in_sizes, int n_in,
                              void* d_out, int out_size, void* d_ws, size_t ws_size,
                              hipStream_t stream)
{
    const float* x          = (const float*)d_in[0];
    const float* W_xp       = (const float*)d_in[1];
    const float* W_dt       = (const float*)d_in[2];
    const float* b_dt       = (const float*)d_in[3];
    const float* A_log      = (const float*)d_in[4];
    const float* D_param    = (const float*)d_in[5];
    const float* alpha      = (const float*)d_in[6];
    const float* beta_logit = (const float*)d_in[7];
    float* out = (float*)d_out;

    float* ws = (float*)d_ws;
    float*  dtw  = ws;                                    // 2,097,152 floats
    float*  Bp   = dtw + (size_t)L_SEQ * D_INNER;         // 65,536
    float*  Cp   = Bp + (size_t)L_SEQ * D_STATE;          // 65,536
    float4* GTUW = (float4*)(Cp + (size_t)L_SEQ * D_STATE);         // 4,194,304 floats
    float*  scpp = (float*)GTUW + (size_t)4 * NCHUNK * NCH;         // 2,097,152 floats
    float2* SC        = (float2*)scpp;   // used by k2b/k2c (late)
    float*  proj_part = scpp;            // used by k1a/k1b (early) — aliased, disjoint lifetime
    // total = 8,519,680 floats ≈ 34.1 MB

    k1a<<<dim3(L_SEQ / 64, 8), 256, 0, stream>>>(x, W_xp, proj_part);
    k1b<<<L_SEQ / 16, 256, 0, stream>>>(proj_part, W_dt, b_dt, dtw, Bp, Cp);
    k2a<<<dim3(NCHUNK, D_INNER / 64), 256, 0, stream>>>(
        x, dtw, Bp, A_log, alpha, beta_logit, GTUW);
    k2b<<<NCH / 64, 64, 0, stream>>>(GTUW, SC);
    k2c<<<dim3(NCHUNK, D_INNER / 64), 256, 0, stream>>>(
        x, dtw, Bp, Cp, A_log, D_param, alpha, beta_logit, SC, out);
}